// Round 3
// baseline (111.870 us; speedup 1.0000x reference)
//
#include <hip/hip_runtime.h>

// NewSupConLoss: B=512, L=20, D=128. Gram N=10240, fused exp/reduce.
// Round 3: no LDS, no barriers. bf16 matrix (2.6 MB) is L2-resident; B frags
// load straight from L2 into registers (per-kk double buffer), A persistent.
// Grid (80 ta, 20 c): block = 128-row strip x 512 cols (one class), flush once.

#define NB 512
#define NL 20
#define ND 128
#define NROW (NB * NL)            // 10240
#define FBYTES (NROW * 256)       // 2,621,440
#define SCALE 4.5398160f          // sqrt(log2(e)/0.07); dot feeds v_exp_f32 directly
#define LN2 0.69314718056f        // converts scaled dot -> dot/T for W

typedef float f32x4 __attribute__((ext_vector_type(4)));
typedef short short8 __attribute__((ext_vector_type(8)));
typedef unsigned short ushort4v __attribute__((ext_vector_type(4)));

static __device__ __forceinline__ unsigned short f2bf(float x) {
  unsigned int b = __float_as_uint(x);
  b += 0x7FFFu + ((b >> 16) & 1u);
  return (unsigned short)(b >> 16);
}

static __device__ __forceinline__ float fexp2(float x) {
#if __has_builtin(__builtin_amdgcn_exp2f)
  return __builtin_amdgcn_exp2f(x);
#else
  return exp2f(x);
#endif
}

// fp32 [B,L,D] -> bf16 rows a=l*512+i (LINEAR layout), scaled by SCALE.
// Also zeroes S (10240 f32) + W (512 f32).
__global__ __launch_bounds__(256) void k_convert(const float* __restrict__ feat,
                                                 unsigned char* __restrict__ fb,
                                                 float* __restrict__ zbuf) {
  int t = blockIdx.x * 256 + threadIdx.x;   // [0, 327680)
  if (t < 10752) zbuf[t] = 0.f;
  int q = t & 31;
  int a = t >> 5;
  int l = a >> 9;
  int i = a & 511;
  const float* src = feat + (size_t)i * (NL * ND) + l * ND + q * 4;
  float4 v = *(const float4*)src;
  ushort4v u;
  u.x = f2bf(v.x * SCALE); u.y = f2bf(v.y * SCALE);
  u.z = f2bf(v.z * SCALE); u.w = f2bf(v.w * SCALE);
  *(ushort4v*)(fb + a * 256 + q * 8) = u;
}

__global__ __launch_bounds__(256, 2) void k_gram(const unsigned char* __restrict__ F,
                                                 const int* __restrict__ labels,
                                                 float* __restrict__ S,
                                                 float* __restrict__ W) {
  const int ta = blockIdx.x;   // row strip [ta*128, +128)
  const int c = blockIdx.y;    // class: cols [c*512, +512) = 4 tiles
  const int tid = threadIdx.x;
  const int lane = tid & 63, w = tid >> 6;
  const int fr = lane & 15, kg = lane >> 4;
  const int wr = (w >> 1) * 64, wc = (w & 1) * 64;
  const int l = ta >> 2;
  const bool lc = (c == l);

  // ---- persistent A fragments: 16 x short8 = 64 VGPR (L2-hot after first block) ----
  short8 af[4][4];   // [kk][m]
#pragma unroll
  for (int kk = 0; kk < 4; ++kk)
#pragma unroll
    for (int m = 0; m < 4; ++m)
      af[kk][m] = *(const short8*)(F + (size_t)(ta * 128 + wr + m * 16 + fr) * 256 +
                                   kk * 64 + kg * 16);

  float esum[4][4] = {};   // [m][reg]
  float wsum[4][4] = {};

#pragma unroll
  for (int t = 0; t < 4; ++t) {
    const int tb = c * 4 + t;
    // per-lane B base: row (wc + n*16 + fr), K-chunk (kk*64 + kg*16)
    const unsigned char* bw = F + (size_t)tb * 32768 + (wc + fr) * 256 + kg * 16;

#define LOADB(DST, KK)                                                      \
  _Pragma("unroll") for (int n = 0; n < 4; ++n)                             \
      DST[n] = *(const short8*)(bw + n * 4096 + (KK) * 64);
#define STEP(BUF, KK)                                                       \
  _Pragma("unroll") for (int m = 0; m < 4; ++m)                             \
  _Pragma("unroll") for (int n = 0; n < 4; ++n)                             \
      acc[m][n] = __builtin_amdgcn_mfma_f32_16x16x32_bf16(af[KK][m], BUF[n],\
                                                          acc[m][n], 0, 0, 0);
    f32x4 acc[4][4] = {};
    short8 b0[4], b1[4];
    LOADB(b0, 0)
    LOADB(b1, 1)
    STEP(b0, 0)
    LOADB(b0, 2)
    STEP(b1, 1)
    LOADB(b1, 3)
    STEP(b0, 2)
    STEP(b1, 3)
#undef LOADB
#undef STEP

    // ---- epilogue: exp + register accumulate ----
    // i==j mask hits when global row == col (mod 512): tb&3==ta&3 -> t==ta&3.
    const bool maskstep = (t == (ta & 3));

#define EPI(MASKED)                                                         \
  _Pragma("unroll") for (int m = 0; m < 4; ++m)                             \
  _Pragma("unroll") for (int reg = 0; reg < 4; ++reg) {                     \
    const int row_l = wr + m * 16 + kg * 4 + reg;                           \
    float e = 0.f;                                                          \
    _Pragma("unroll") for (int n = 0; n < 4; ++n) {                         \
      float ex = fexp2(acc[m][n][reg]);                                     \
      if (MASKED && row_l == (wc + n * 16 + fr)) ex = 0.f;                  \
      e += ex;                                                              \
    }                                                                       \
    esum[m][reg] += e;                                                      \
  }
    if (maskstep) { EPI(1) } else { EPI(0) }
#undef EPI

    if (lc) {   // numerator/W accumulation (1/20 of blocks)
      float labj[4];
#pragma unroll
      for (int n = 0; n < 4; ++n)
        labj[n] = (float)labels[((t * 128 + wc + n * 16 + fr) & 511) * NL + c];
#pragma unroll
      for (int m = 0; m < 4; ++m)
#pragma unroll
        for (int reg = 0; reg < 4; ++reg) {
          const int row_l = wr + m * 16 + kg * 4 + reg;
          float ws = 0.f;
#pragma unroll
          for (int n = 0; n < 4; ++n) {
            float gv = acc[m][n][reg];
            bool dg = maskstep && (row_l == (wc + n * 16 + fr));
            ws += dg ? 0.f : gv * labj[n];
          }
          wsum[m][reg] += ws;
        }
    }
  }

  // ---- flush: shfl-reduce over fr (cols) + one atomic per row per wave ----
#pragma unroll
  for (int m = 0; m < 4; ++m)
#pragma unroll
    for (int reg = 0; reg < 4; ++reg) {
      float e = esum[m][reg];
      e += __shfl_xor(e, 1, 64); e += __shfl_xor(e, 2, 64);
      e += __shfl_xor(e, 4, 64); e += __shfl_xor(e, 8, 64);
      float ww = 0.f;
      if (lc) {
        ww = wsum[m][reg];
        ww += __shfl_xor(ww, 1, 64); ww += __shfl_xor(ww, 2, 64);
        ww += __shfl_xor(ww, 4, 64); ww += __shfl_xor(ww, 8, 64);
      }
      if (fr == 0) {
        const int i = (ta * 128 + wr + m * 16 + kg * 4 + reg) & 511;
        atomicAdd(S + c * NB + i, e);
        if (lc && labels[i * NL + c] != 0 && ww != 0.f)
          atomicAdd(W + i, ww * LN2);
      }
    }
}

// Per-anchor combine + mean. One block, 512 threads.
__global__ __launch_bounds__(512) void k_final(const float* __restrict__ S,
                                               const float* __restrict__ W,
                                               const int* __restrict__ labels,
                                               float* __restrict__ out) {
  __shared__ float cnt[NL];
  __shared__ float red[8];
  const int i = threadIdx.x;
  if (i < NL) cnt[i] = 0.f;
  __syncthreads();
  int lab[NL];
#pragma unroll
  for (int cI = 0; cI < NL; ++cI) lab[cI] = labels[i * NL + cI];
#pragma unroll
  for (int cI = 0; cI < NL; ++cI)
    if (lab[cI]) atomicAdd(&cnt[cI], 1.f);
  __syncthreads();
  float avg = 0.f, ls = 0.f;
#pragma unroll
  for (int cI = 0; cI < NL; ++cI) {
    if (lab[cI]) {
      float wgt = cnt[cI] - 1.f;
      avg += wgt;
      ls += wgt * logf(S[cI * NB + i]);
    }
  }
  float v = (W[i] - ls) / (avg == 0.f ? 1.f : avg);
#pragma unroll
  for (int s = 1; s < 64; s <<= 1) v += __shfl_xor(v, s, 64);
  if ((i & 63) == 0) red[i >> 6] = v;
  __syncthreads();
  if (i == 0) {
    float tot = 0.f;
#pragma unroll
    for (int k = 0; k < 8; ++k) tot += red[k];
    out[0] = -(tot / (float)NB);
  }
}

extern "C" void kernel_launch(void* const* d_in, const int* in_sizes, int n_in,
                              void* d_out, int out_size, void* d_ws, size_t ws_size,
                              hipStream_t stream) {
  const float* feat = (const float*)d_in[0];
  const int* labels = (const int*)d_in[1];
  float* out = (float*)d_out;
  unsigned char* ws = (unsigned char*)d_ws;
  unsigned char* fb = ws;
  float* S = (float*)(ws + FBYTES);
  float* W = S + NL * NB;

  k_convert<<<NROW * 32 / 256, 256, 0, stream>>>(feat, fb, S);
  dim3 grid(80, 20);
  k_gram<<<grid, 256, 0, stream>>>(fb, labels, S, W);
  k_final<<<1, 512, 0, stream>>>(S, W, labels, out);
}

// Round 4
// 109.624 us; speedup vs baseline: 1.0205x; 1.0205x over previous
//
#include <hip/hip_runtime.h>

// NewSupConLoss: B=512, L=20, D=128. Gram N=10240, fused exp/reduce.
// Round 4: symmetric triangle (3240 tiles of 128x128, ta<=tb) with dual
// row+col credits; 512-thread 8-wave blocks; A+B tiles in LDS (64KB, two
// blocks/CU -> 16 waves/CU); persistent chunked schedule over grid=512.

#define NB 512
#define NL 20
#define ND 128
#define NROW (NB * NL)            // 10240
#define FBYTES (NROW * 256)       // 2,621,440
#define NTILE 80
#define TRI_TOTAL 3240            // 80*81/2
#define GRID_G 512
#define SCALE 4.5398160f          // sqrt(log2(e)/0.07); dot feeds exp2 directly
#define LN2 0.69314718056f        // scaled dot -> dot/T

typedef float f32x4 __attribute__((ext_vector_type(4)));
typedef short short8 __attribute__((ext_vector_type(8)));
typedef unsigned short ushort4v __attribute__((ext_vector_type(4)));

static __device__ __forceinline__ unsigned short f2bf(float x) {
  unsigned int b = __float_as_uint(x);
  b += 0x7FFFu + ((b >> 16) & 1u);
  return (unsigned short)(b >> 16);
}

static __device__ __forceinline__ float fexp2(float x) {
#if __has_builtin(__builtin_amdgcn_exp2f)
  return __builtin_amdgcn_exp2f(x);
#else
  return exp2f(x);
#endif
}

// fp32 [B,L,D] -> bf16 rows a=l*512+i, scaled, XOR-swizzled per 256B row.
// Also zeroes S (10240 f32) + W (512 f32).
__global__ __launch_bounds__(256) void k_convert(const float* __restrict__ feat,
                                                 unsigned char* __restrict__ fswz,
                                                 float* __restrict__ zbuf) {
  int t = blockIdx.x * 256 + threadIdx.x;   // [0, 327680)
  if (t < 10752) zbuf[t] = 0.f;
  int q = t & 31;
  int a = t >> 5;
  int l = a >> 9;
  int i = a & 511;
  const float* src = feat + (size_t)i * (NL * ND) + l * ND + q * 4;
  float4 v = *(const float4*)src;
  ushort4v u;
  u.x = f2bf(v.x * SCALE); u.y = f2bf(v.y * SCALE);
  u.z = f2bf(v.z * SCALE); u.w = f2bf(v.w * SCALE);
  int dst = a * 256 + ((q * 8) ^ ((a & 7) << 4));
  *(ushort4v*)(fswz + dst) = u;
}

__global__ __launch_bounds__(512, 4) void k_gram(const unsigned char* __restrict__ fswz,
                                                 const int* __restrict__ labels,
                                                 float* __restrict__ S,
                                                 float* __restrict__ W) {
  __shared__ unsigned char ldsA[32768];
  __shared__ unsigned char ldsB[32768];
  const int tid = threadIdx.x;
  const int lane = tid & 63, w = tid >> 6;   // 8 waves
  const int fr = lane & 15, kg = lane >> 4;
  const int wr = (w >> 2) * 64;              // 2 row-groups of 64
  const int wc = (w & 3) * 32;               // 4 col-groups of 32
  const int xr = (fr & 7) << 4;

  // contiguous triangular chunk [s0, s1)
  const int b = blockIdx.x;
  int s0 = (b * TRI_TOTAL) / GRID_G;
  const int s1 = ((b + 1) * TRI_TOTAL) / GRID_G;
  int ta = 0, base = 0;
  while (base + (NTILE - ta) <= s0) { base += NTILE - ta; ++ta; }
  int tb = ta + (s0 - base);

  auto stageT = [&](unsigned char* dst, int t) {
    const unsigned char* g = fswz + (size_t)t * 32768 + w * 4096 + lane * 16;
    unsigned char* l = dst + w * 4096;        // wave-uniform LDS base
#pragma unroll
    for (int p = 0; p < 4; ++p)
      __builtin_amdgcn_global_load_lds(
          (const __attribute__((address_space(1))) unsigned int*)(g + p * 1024),
          (__attribute__((address_space(3))) unsigned int*)(l + p * 1024), 16, 0, 0);
  };

  stageT(ldsA, ta);
  if (tb != ta) stageT(ldsB, tb);
  __syncthreads();   // drains vmcnt(0)

  float esum[4][4] = {};   // row partials (this wave's 32 cols), per class run
  float wrow[4][4] = {};
  float ccol[2] = {}, wcol[2] = {};
  int ccls = tb >> 2;

  for (int s = s0; s < s1; ++s) {
    const unsigned char* lB = (tb == ta) ? (const unsigned char*)ldsA
                                         : (const unsigned char*)ldsB;
    const int lcls = ta >> 2;
    const bool samecls = (lcls == (tb >> 2));
    const bool maskstep = ((ta & 3) == (tb & 3));

    // ---- MFMA: wave computes 64x32 (m=4, n=2) ----
    f32x4 acc[4][2] = {};
#pragma unroll
    for (int kk = 0; kk < 4; ++kk) {
      const int kb = (kk * 64 + kg * 16) ^ xr;
      short8 af[4], bf[2];
#pragma unroll
      for (int m = 0; m < 4; ++m)
        af[m] = *(const short8*)(ldsA + (wr + m * 16 + fr) * 256 + kb);
#pragma unroll
      for (int n = 0; n < 2; ++n)
        bf[n] = *(const short8*)(lB + (wc + n * 16 + fr) * 256 + kb);
#pragma unroll
      for (int m = 0; m < 4; ++m)
#pragma unroll
        for (int n = 0; n < 2; ++n)
          acc[m][n] = __builtin_amdgcn_mfma_f32_16x16x32_bf16(af[m], bf[n], acc[m][n], 0, 0, 0);
    }

    // ---- labels (same-class tiles only: ~200 of 3240) ----
    unsigned li_mask = 0;
    float lj[2] = {0.f, 0.f};
    if (samecls) {
#pragma unroll
      for (int m = 0; m < 4; ++m)
#pragma unroll
        for (int reg = 0; reg < 4; ++reg) {
          int i = (ta * 128 + wr + m * 16 + kg * 4 + reg) & 511;
          li_mask |= (unsigned)(labels[i * NL + lcls] & 1) << (m * 4 + reg);
        }
#pragma unroll
      for (int n = 0; n < 2; ++n)
        lj[n] = (float)labels[(((tb & 3) * 128 + wc + n * 16 + fr)) * NL + lcls];
    }

    // ---- epilogue: exp + dual accumulate ----
#define EPI(MASKED)                                                          \
  _Pragma("unroll") for (int m = 0; m < 4; ++m)                              \
  _Pragma("unroll") for (int reg = 0; reg < 4; ++reg) {                      \
    const int row_l = wr + m * 16 + kg * 4 + reg;                            \
    _Pragma("unroll") for (int n = 0; n < 2; ++n) {                          \
      float g = acc[m][n][reg];                                              \
      bool dg = MASKED && (row_l == (wc + n * 16 + fr));                     \
      float ex = dg ? 0.f : fexp2(g);                                        \
      esum[m][reg] += ex;                                                    \
      ccol[n] += ex;                                                         \
      if (samecls) {                                                         \
        float gm = dg ? 0.f : g;                                             \
        wrow[m][reg] += gm * lj[n];                                          \
        wcol[n] += ((li_mask >> (m * 4 + reg)) & 1) ? gm : 0.f;              \
      }                                                                      \
    }                                                                        \
  }
    if (maskstep) { EPI(true) } else { EPI(false) }
#undef EPI

    // ---- per-tile col credit (mirror), off-diag only ----
    if (ta != tb) {
#pragma unroll
      for (int n = 0; n < 2; ++n) {
        float e = ccol[n];
        e += __shfl_xor(e, 16, 64); e += __shfl_xor(e, 32, 64);
        float wv = 0.f;
        if (samecls) {
          wv = wcol[n];
          wv += __shfl_xor(wv, 16, 64); wv += __shfl_xor(wv, 32, 64);
        }
        if (kg == 0) {
          int j = ((tb & 3) * 128 + wc + n * 16 + fr);
          atomicAdd(S + lcls * NB + j, e);
          if (samecls && lj[n] != 0.f && wv != 0.f)
            atomicAdd(W + j, wv * LN2);
        }
      }
    }
#pragma unroll
    for (int n = 0; n < 2; ++n) { ccol[n] = 0.f; wcol[n] = 0.f; }

    // ---- advance + row flush at class-run boundary ----
    int nta = ta, ntb = tb + 1;
    if (ntb == NTILE) { ++nta; ntb = nta; }
    const bool last = (s + 1 == s1);
    if (last || nta != ta || (ntb >> 2) != ccls) {
      const bool runSame = (lcls == ccls);
#pragma unroll
      for (int m = 0; m < 4; ++m)
#pragma unroll
        for (int reg = 0; reg < 4; ++reg) {
          float e = esum[m][reg];
          e += __shfl_xor(e, 1, 64); e += __shfl_xor(e, 2, 64);
          e += __shfl_xor(e, 4, 64); e += __shfl_xor(e, 8, 64);
          float wv = 0.f;
          if (runSame) {
            wv = wrow[m][reg];
            wv += __shfl_xor(wv, 1, 64); wv += __shfl_xor(wv, 2, 64);
            wv += __shfl_xor(wv, 4, 64); wv += __shfl_xor(wv, 8, 64);
          }
          if (fr == 0) {
            int i = (ta * 128 + wr + m * 16 + kg * 4 + reg) & 511;
            atomicAdd(S + ccls * NB + i, e);
            if (runSame && ((li_mask >> (m * 4 + reg)) & 1) && wv != 0.f)
              atomicAdd(W + i, wv * LN2);
          }
          esum[m][reg] = 0.f;
          wrow[m][reg] = 0.f;
        }
    }

    if (!last) {
      __syncthreads();                       // all LDS reads done
      if (nta != ta) stageT(ldsA, nta);
      if (ntb != nta) stageT(ldsB, ntb);
      __syncthreads();                       // vmcnt drained
      ta = nta; tb = ntb; ccls = ntb >> 2;
    }
  }
}

// Per-anchor combine + mean. One block, 512 threads.
__global__ __launch_bounds__(512) void k_final(const float* __restrict__ S,
                                               const float* __restrict__ W,
                                               const int* __restrict__ labels,
                                               float* __restrict__ out) {
  __shared__ float cnt[NL];
  __shared__ float red[8];
  const int i = threadIdx.x;
  if (i < NL) cnt[i] = 0.f;
  __syncthreads();
  int lab[NL];
#pragma unroll
  for (int cI = 0; cI < NL; ++cI) lab[cI] = labels[i * NL + cI];
#pragma unroll
  for (int cI = 0; cI < NL; ++cI)
    if (lab[cI]) atomicAdd(&cnt[cI], 1.f);
  __syncthreads();
  float avg = 0.f, ls = 0.f;
#pragma unroll
  for (int cI = 0; cI < NL; ++cI) {
    if (lab[cI]) {
      float wgt = cnt[cI] - 1.f;
      avg += wgt;
      ls += wgt * logf(S[cI * NB + i]);
    }
  }
  float v = (W[i] - ls) / (avg == 0.f ? 1.f : avg);
#pragma unroll
  for (int s = 1; s < 64; s <<= 1) v += __shfl_xor(v, s, 64);
  if ((i & 63) == 0) red[i >> 6] = v;
  __syncthreads();
  if (i == 0) {
    float tot = 0.f;
#pragma unroll
    for (int k = 0; k < 8; ++k) tot += red[k];
    out[0] = -(tot / (float)NB);
  }
}

extern "C" void kernel_launch(void* const* d_in, const int* in_sizes, int n_in,
                              void* d_out, int out_size, void* d_ws, size_t ws_size,
                              hipStream_t stream) {
  const float* feat = (const float*)d_in[0];
  const int* labels = (const int*)d_in[1];
  float* out = (float*)d_out;
  unsigned char* ws = (unsigned char*)d_ws;
  unsigned char* fswz = ws;
  float* S = (float*)(ws + FBYTES);
  float* W = S + NL * NB;

  k_convert<<<NROW * 32 / 256, 256, 0, stream>>>(feat, fswz, S);
  k_gram<<<GRID_G, 512, 0, stream>>>(fswz, labels, S, W);
  k_final<<<1, 512, 0, stream>>>(S, W, labels, out);
}

// Round 5
// 83.512 us; speedup vs baseline: 1.3396x; 1.3127x over previous
//
#include <hip/hip_runtime.h>

// NewSupConLoss: B=512, L=20, D=128. Gram N=10240, fused exp/reduce.
// Round 5: ZERO atomics. Grid (80 ta, 10 g): block = 128-row strip x 1024 cols
// (2 full classes), so every (class, strip, col-half) partial has exactly one
// writer -> plain stores into Pr/Pw, reduced by k_reduce/k_final.
// 8-wave 512-thread blocks, wave = 32 rows x 64 cols, A persistent in regs,
// B double-buffered in LDS (2x32KB) -> 2 blocks/CU, 16 waves/CU.

#define NB 512
#define NL 20
#define NROW (NB * NL)            // 10240
#define FBYTES (NROW * 256)       // 2,621,440
#define SCALE 4.5398160f          // sqrt(log2(e)/0.07); dot feeds exp2 directly
#define LN2 0.69314718056f        // scaled dot -> dot/T

typedef float f32x4 __attribute__((ext_vector_type(4)));
typedef short short8 __attribute__((ext_vector_type(8)));
typedef unsigned short ushort4v __attribute__((ext_vector_type(4)));

static __device__ __forceinline__ unsigned short f2bf(float x) {
  unsigned int b = __float_as_uint(x);
  b += 0x7FFFu + ((b >> 16) & 1u);
  return (unsigned short)(b >> 16);
}

static __device__ __forceinline__ float fexp2(float x) {
#if __has_builtin(__builtin_amdgcn_exp2f)
  return __builtin_amdgcn_exp2f(x);
#else
  return exp2f(x);
#endif
}

// fp32 [B,L,D] -> bf16 rows a=l*512+i, scaled, XOR-swizzled per 256B row.
__global__ __launch_bounds__(256) void k_convert(const float* __restrict__ feat,
                                                 unsigned char* __restrict__ fswz) {
  int t = blockIdx.x * 256 + threadIdx.x;   // [0, 327680)
  int q = t & 31;
  int a = t >> 5;
  int l = a >> 9;
  int i = a & 511;
  const float* src = feat + (size_t)i * (NL * 128) + l * 128 + q * 4;
  float4 v = *(const float4*)src;
  ushort4v u;
  u.x = f2bf(v.x * SCALE); u.y = f2bf(v.y * SCALE);
  u.z = f2bf(v.z * SCALE); u.w = f2bf(v.w * SCALE);
  int dst = a * 256 + ((q * 8) ^ ((a & 7) << 4));
  *(ushort4v*)(fswz + dst) = u;
}

// Pr[c][ta][wcg][r] : c<20, ta<80, wcg<2, r<128  (partial row-sums of exp)
// Pw[c][wcg][i]     : c<20, wcg<2, i<512         (numerator partials, l==c strips)
__global__ __launch_bounds__(512, 4) void k_gram(const unsigned char* __restrict__ fswz,
                                                 const int* __restrict__ labels,
                                                 float* __restrict__ Pr,
                                                 float* __restrict__ Pw) {
  __shared__ unsigned char lds[65536];   // two 32KB B buffers
  const int ta = blockIdx.x;             // row strip [ta*128, +128)
  const int g = blockIdx.y;              // col group: tiles [8g, 8g+8) = classes 2g,2g+1
  const int tid = threadIdx.x;
  const int lane = tid & 63, w = tid >> 6;   // 8 waves
  const int fr = lane & 15, kg = lane >> 4;
  const int wr = (w & 3) * 32;           // 4 row groups of 32
  const int wc = (w >> 2) * 64;          // 2 col groups of 64
  const int wcg = w >> 2;
  const int xr = (fr & 7) << 4;
  const int l = ta >> 2;

  // ---- persistent A fragments: 8 x short8 = 32 VGPR ----
  short8 af[4][2];   // [kk][m]
#pragma unroll
  for (int kk = 0; kk < 4; ++kk)
#pragma unroll
    for (int m = 0; m < 2; ++m)
      af[kk][m] = *(const short8*)(fswz + (size_t)(ta * 128 + wr + m * 16 + fr) * 256 +
                                   ((kk * 64 + kg * 16) ^ xr));

  auto stage = [&](int buf, int tb) {
    const unsigned char* gB = fswz + (size_t)tb * 32768 + w * 4096 + lane * 16;
    unsigned char* lB = lds + buf * 32768 + w * 4096;   // wave-uniform LDS base
#pragma unroll
    for (int p = 0; p < 4; ++p)
      __builtin_amdgcn_global_load_lds(
          (const __attribute__((address_space(1))) unsigned int*)(gB + p * 1024),
          (__attribute__((address_space(3))) unsigned int*)(lB + p * 1024), 16, 0, 0);
  };

  const int tb0 = g * 8;
  stage(0, tb0);
  __syncthreads();   // buf0 ready

  float esum[2][4] = {};   // [m][reg] row partials over this wave's 64 cols
  float wsum[2][4] = {};
  int cur = 0;

#pragma unroll
  for (int t = 0; t < 8; ++t) {
    const int tb = tb0 + t;
    if (t < 7) stage(cur ^ 1, tb + 1);   // prefetch next tile

    // ---- B frags + MFMA: wave computes 32x64 ----
    const unsigned char* lb = lds + cur * 32768;
    f32x4 acc[2][4] = {};
#pragma unroll
    for (int kk = 0; kk < 4; ++kk) {
      const int kb = (kk * 64 + kg * 16) ^ xr;
      short8 bf[4];
#pragma unroll
      for (int n = 0; n < 4; ++n)
        bf[n] = *(const short8*)(lb + (wc + n * 16 + fr) * 256 + kb);
#pragma unroll
      for (int m = 0; m < 2; ++m)
#pragma unroll
        for (int n = 0; n < 4; ++n)
          acc[m][n] = __builtin_amdgcn_mfma_f32_16x16x32_bf16(af[kk][m], bf[n], acc[m][n], 0, 0, 0);
    }

    const int c = tb >> 2;
    const bool lc = (c == l);
    const bool maskstep = ((tb & 3) == (ta & 3));   // diag (i==j) possible

    // ---- epilogue: exp + register accumulate ----
#define EPI(MASKED)                                                          \
  _Pragma("unroll") for (int m = 0; m < 2; ++m)                              \
  _Pragma("unroll") for (int reg = 0; reg < 4; ++reg) {                      \
    const int row_l = wr + m * 16 + kg * 4 + reg;                            \
    float e = 0.f;                                                           \
    _Pragma("unroll") for (int n = 0; n < 4; ++n) {                          \
      float ex = fexp2(acc[m][n][reg]);                                      \
      if (MASKED && row_l == (wc + n * 16 + fr)) ex = 0.f;                   \
      e += ex;                                                               \
    }                                                                        \
    esum[m][reg] += e;                                                       \
  }
    if (maskstep) { EPI(1) } else { EPI(0) }
#undef EPI

    if (lc) {   // numerator accumulation (1/10 of blocks, 4 of 8 tiles)
      float lj[4];
#pragma unroll
      for (int n = 0; n < 4; ++n)
        lj[n] = (float)labels[((tb & 3) * 128 + wc + n * 16 + fr) * NL + c];
#pragma unroll
      for (int m = 0; m < 2; ++m)
#pragma unroll
        for (int reg = 0; reg < 4; ++reg) {
          const int row_l = wr + m * 16 + kg * 4 + reg;
          float ws = 0.f;
#pragma unroll
          for (int n = 0; n < 4; ++n) {
            float gv = acc[m][n][reg];
            bool dg = maskstep && (row_l == (wc + n * 16 + fr));
            ws += dg ? 0.f : gv * lj[n];
          }
          wsum[m][reg] += ws;
        }
    }

    // ---- class-boundary flush: shfl over fr + plain stores (no atomics) ----
    if ((t & 3) == 3) {
#pragma unroll
      for (int m = 0; m < 2; ++m)
#pragma unroll
        for (int reg = 0; reg < 4; ++reg) {
          float e = esum[m][reg];
          e += __shfl_xor(e, 1, 64); e += __shfl_xor(e, 2, 64);
          e += __shfl_xor(e, 4, 64); e += __shfl_xor(e, 8, 64);
          float wv = 0.f;
          if (lc) {
            wv = wsum[m][reg];
            wv += __shfl_xor(wv, 1, 64); wv += __shfl_xor(wv, 2, 64);
            wv += __shfl_xor(wv, 4, 64); wv += __shfl_xor(wv, 8, 64);
          }
          if (fr == 0) {
            const int r = wr + m * 16 + kg * 4 + reg;   // 0..127
            Pr[((c * 80 + ta) * 2 + wcg) * 128 + r] = e;
            if (lc) Pw[(c * 2 + wcg) * 512 + (ta & 3) * 128 + r] = wv;
          }
          esum[m][reg] = 0.f;
          wsum[m][reg] = 0.f;
        }
    }

    __syncthreads();   // staged buf ready; LDS reads of cur done
    cur ^= 1;
  }
}

// Slog[c][i] = log( sum over 20 strips x 2 col-halves of Pr )
__global__ __launch_bounds__(256) void k_reduce(const float* __restrict__ Pr,
                                                float* __restrict__ Slog) {
  int idx = blockIdx.x * 256 + threadIdx.x;   // [0, 10240)
  int c = idx >> 9, i = idx & 511;
  float s = 0.f;
#pragma unroll
  for (int l2 = 0; l2 < NL; ++l2) {
    const float* p = Pr + ((c * 80 + (l2 * 4 + (i >> 7))) * 2) * 128 + (i & 127);
    s += p[0] + p[128];
  }
  Slog[idx] = logf(s);
}

// Per-anchor combine + mean. One block, 512 threads.
__global__ __launch_bounds__(512) void k_final(const float* __restrict__ Slog,
                                               const float* __restrict__ Pw,
                                               const int* __restrict__ labels,
                                               float* __restrict__ out) {
  __shared__ float cnt[NL];
  __shared__ float red[8];
  const int i = threadIdx.x;
  if (i < NL) cnt[i] = 0.f;
  __syncthreads();
  int lab[NL];
#pragma unroll
  for (int cI = 0; cI < NL; ++cI) lab[cI] = labels[i * NL + cI];
#pragma unroll
  for (int cI = 0; cI < NL; ++cI)
    if (lab[cI]) atomicAdd(&cnt[cI], 1.f);
  __syncthreads();
  float avg = 0.f, acc = 0.f;
#pragma unroll
  for (int cI = 0; cI < NL; ++cI) {
    if (lab[cI]) {
      float wgt = cnt[cI] - 1.f;
      avg += wgt;
      float wnum = (Pw[(cI * 2) * 512 + i] + Pw[(cI * 2 + 1) * 512 + i]) * LN2;
      acc += wnum - wgt * Slog[cI * NB + i];
    }
  }
  float v = acc / (avg == 0.f ? 1.f : avg);
#pragma unroll
  for (int s = 1; s < 64; s <<= 1) v += __shfl_xor(v, s, 64);
  if ((i & 63) == 0) red[i >> 6] = v;
  __syncthreads();
  if (i == 0) {
    float tot = 0.f;
#pragma unroll
    for (int k = 0; k < 8; ++k) tot += red[k];
    out[0] = -(tot / (float)NB);
  }
}

extern "C" void kernel_launch(void* const* d_in, const int* in_sizes, int n_in,
                              void* d_out, int out_size, void* d_ws, size_t ws_size,
                              hipStream_t stream) {
  const float* feat = (const float*)d_in[0];
  const int* labels = (const int*)d_in[1];
  float* out = (float*)d_out;
  unsigned char* ws = (unsigned char*)d_ws;
  unsigned char* fswz = ws;
  float* Pr = (float*)(ws + FBYTES);                   // 20*80*2*128 f32 = 1.6 MB
  float* Pw = Pr + 20 * 80 * 2 * 128;                  // 20*2*512 f32 = 80 KB
  float* Slog = Pw + 20 * 2 * 512;                     // 10240 f32 = 40 KB

  k_convert<<<NROW * 32 / 256, 256, 0, stream>>>(feat, fswz);
  dim3 grid(80, 10);
  k_gram<<<grid, 512, 0, stream>>>(fswz, labels, Pr, Pw);
  k_reduce<<<NROW / 256, 256, 0, stream>>>(Pr, Slog);
  k_final<<<1, 512, 0, stream>>>(Slog, Pw, labels, out);
}